// Round 10
// baseline (208.719 us; speedup 1.0000x reference)
//
#include <hip/hip_runtime.h>

#define B_     8
#define LV_    4096
#define D_     256
#define N_     2048
#define P_     32
#define WROWS_ 64                      // rows per LDS window (64 KB tile)
#define SEGS_  4                       // segments per window
#define NWIN_  (B_ * (LV_ / WROWS_))   // 512 windows
#define NBLK_  (NWIN_ * SEGS_)         // 2048 blocks (R7's proven macro-shape)
#define LCAP_  4096                    // LDS bin-list capacity (mean K=128)

typedef float v4f __attribute__((ext_vector_type(4)));

__device__ __forceinline__ float lane_bcast_f(float v, int l) {
    return __int_as_float(__builtin_amdgcn_readlane(__float_as_int(v), l));
}

// First row touched by bin (n,p) — same clamping as the main math. This IS
// the ownership function: window containing r_first owns the bin; every
// block evaluates it identically -> each bin processed exactly once.
__device__ __forceinline__ int bin_r_first(const float* __restrict__ boxes, int n, int p) {
    const float y1 = boxes[2 * n], y2 = boxes[2 * n + 1];
    const float bin_h = (y2 - y1) * (1.0f / (float)P_);
    const int gh = (int)ceilf(bin_h);
    if (gh < 1) return 0;
    const float sub  = bin_h / (float)gh;
    const float boff = (y1 - 0.5f) + (float)p * bin_h;
    const float a    = fmaf(0.5f, sub, boff);
    int r = (int)floorf(a);
    if (r < 0) r = 0;
    if (r > LV_ - 1) r = LV_ - 1;
    return r;
}

// Pass 1: counting-sort boxes by batch into order[] + batch offsets offs[9].
__global__ __launch_bounds__(256) void build_order_kernel(
    const int* __restrict__ batch_idx, int* __restrict__ order, int* __restrict__ offs)
{
    __shared__ int cnt[B_], cur[B_];
    const int tid = threadIdx.x;
    if (tid < B_) cnt[tid] = 0;
    __syncthreads();
    for (int n = tid; n < N_; n += 256) atomicAdd(&cnt[batch_idx[n]], 1);
    __syncthreads();
    if (tid == 0) {
        int s = 0;
        for (int b = 0; b < B_; ++b) { cur[b] = s; offs[b] = s; s += cnt[b]; }
        offs[B_] = s;
    }
    __syncthreads();
    for (int n = tid; n < N_; n += 256)
        order[atomicAdd(&cur[batch_idx[n]], 1)] = n;
}

// Per-bin accumulation: identical math to R5..R9 (same absmax). Rows in
// [wlo, wlo+WROWS_) come from the LDS tile, others from global.
__device__ __forceinline__ void process_bin(
    const float* __restrict__ feat, const float* __restrict__ boxes,
    const int* __restrict__ batch_idx, float* __restrict__ out,
    const v4f* tile, int wb, int wlo, int idx, int lane)
{
    const int n = idx >> 5, p = idx & 31;
    const int bi = __builtin_amdgcn_readfirstlane(batch_idx[n]);

    const float y1 = boxes[2 * n], y2 = boxes[2 * n + 1];
    const float bin_h = (y2 - y1) * (1.0f / (float)P_);
    const int gh = (int)ceilf(bin_h);

    const v4f* prow = (const v4f*)feat + (long)bi * (LV_ * (D_ / 4));
    v4f acc0 = {0.f,0.f,0.f,0.f}, acc1 = {0.f,0.f,0.f,0.f};

    if (gh >= 1) {
        const float cntf = (float)gh, sub = bin_h / cntf, inv_sub = 1.0f / sub;
        const float halfsub = 0.5f * sub;
        const float boff = (y1 - 0.5f) + (float)p * bin_h;
        const float a = fmaf(0.5f, sub, boff), ylast = fmaf(cntf - 0.5f, sub, boff);

        int r_first = (int)floorf(a);
        if (r_first < 0) r_first = 0; if (r_first > LV_-1) r_first = LV_-1;
        int r_last = (int)floorf(ylast) + 1;
        if (r_last > LV_-1) r_last = LV_-1; if (r_last < r_first) r_last = r_first;
        const int r0 = __builtin_amdgcn_readfirstlane(r_first);
        const int rl = __builtin_amdgcn_readfirstlane(r_last);
        const float lanef = (float)lane;

        for (int gbase = r0; gbase <= rl; gbase += 64) {
            int kmax = rl - gbase; if (kmax > 63) kmax = 63;

            // lane-parallel closed-form weights (2nd difference of prefix area)
            const int   r  = gbase + lane;
            const float d0 = ((float)gbase + lanef) - a;
            const float dm = d0 - 1.0f, dp = d0 + 1.0f;
            const float nm = fminf(fmaxf(ceilf(dm * inv_sub), 0.0f), cntf);
            const float n0 = fminf(fmaxf(ceilf(d0 * inv_sub), 0.0f), cntf);
            const float np = fminf(fmaxf(ceilf(dp * inv_sub), 0.0f), cntf);
            float Pm = fmaf(nm, dm, -halfsub * fmaf(nm, nm, -nm));
            float P0 = fmaf(n0, d0, -halfsub * fmaf(n0, n0, -n0));
            float Pp = fmaf(np, dp, -halfsub * fmaf(np, np, -np));
            if (r == 0)       Pm = P0;
            if (r == LV_ - 1) Pp = P0 + cntf;
            const float Wl = (Pm + Pp) - 2.0f * P0;

            // split k-range into [0,lo) global | [lo,hi) LDS | [hi,t) global
            const int t = kmax + 1;
            int lo, hi;
            if (tile && bi == wb) {
                lo = wlo - gbase;          lo = lo < 0 ? 0 : (lo > t ? t : lo);
                hi = wlo + WROWS_ - gbase; hi = hi < lo ? lo : (hi > t ? t : hi);
            } else { lo = t; hi = t; }

#define GSEG(KS, KE) do {                                                        \
    int k = (KS);                                                                \
    const v4f* pS = prow + (long)(gbase + k) * (D_ / 4);                         \
    for (; k + 4 <= (KE); k += 4) {                                              \
        v4f v0 = pS[lane], v1 = pS[lane+64], v2 = pS[lane+128], v3 = pS[lane+192];\
        acc0 += v0 * lane_bcast_f(Wl, k);   acc1 += v1 * lane_bcast_f(Wl, k+1);  \
        acc0 += v2 * lane_bcast_f(Wl, k+2); acc1 += v3 * lane_bcast_f(Wl, k+3);  \
        pS += 4 * (D_ / 4); }                                                    \
    for (; k < (KE); ++k) { v4f v = pS[lane]; acc0 += v * lane_bcast_f(Wl, k); pS += (D_ / 4); } \
} while (0)

            GSEG(0, lo);                               // prefix (usually empty)
            {                                          // LDS mid-segment
                int k = lo;
                const v4f* tp = tile + (gbase + lo - wlo) * 64 + lane;
                for (; k + 4 <= hi; k += 4) {
                    v4f t0 = tp[0], t1 = tp[64], t2 = tp[128], t3 = tp[192];
                    acc0 += t0 * lane_bcast_f(Wl, k);   acc1 += t1 * lane_bcast_f(Wl, k+1);
                    acc0 += t2 * lane_bcast_f(Wl, k+2); acc1 += t3 * lane_bcast_f(Wl, k+3);
                    tp += 256;
                }
                for (; k < hi; ++k) { acc0 += tp[0] * lane_bcast_f(Wl, k); tp += 64; }
            }
            GSEG(hi, t);                               // suffix overhang
#undef GSEG
        }
    }

    const float inv_c = 1.0f / (float)(gh > 1 ? gh : 1);
    v4f res = (acc0 + acc1) * inv_c;
    v4f* op = (v4f*)out + ((long)n * P_ + p) * (D_ / 4) + lane;
    __builtin_nontemporal_store(res, op);
}

// Main kernel, R10: block = (window, seg). The block builds the window's bin
// list COOPERATIVELY + DETERMINISTICALLY in LDS (2-pass count/scan/write over
// pairs q=tid+512t), so all 4 seg-blocks hold the identical list and process
// global indices i = seg + 4*wv + 32*t — R7's proven balanced round-robin.
// This isolates R8/R9's regression variable: per-wave box streaming let one
// SHORT box dump all 32 of its bins on a single wave (block time = max over
// waves, 137us); the list interleave spreads them over all 32 wave-slots.
__global__ __launch_bounds__(512) void roi_win_kernel(
    const float* __restrict__ feat, const float* __restrict__ boxes,
    const int* __restrict__ batch_idx, const int* __restrict__ order,
    const int* __restrict__ offs, float* __restrict__ out)
{
    __shared__ v4f tile[WROWS_ * 64];                  // 64 KB
    __shared__ unsigned short list[LCAP_];             // 8 KB (bin ids, 16-bit)
    __shared__ int wsum[9];                            // wave-total scan

    const int tid  = threadIdx.x;
    const int lane = tid & 63;
    const int wv   = tid >> 6;                         // wave 0..7
    const int bid  = blockIdx.x;

    // bijective XCD swizzle: XCD x -> blk [256x,256x+256) -> w [64x,64x+64)
    // -> exactly batch x, resident in its own 4MB L2.
    const int blk = (bid & 7) * (NBLK_ / 8) + (bid >> 3);
    const int w   = blk >> 2;                          // window id
    const int seg = blk & (SEGS_ - 1);
    const int wb  = w >> 6;                            // batch
    const int wt  = w & 63;                            // window index in batch
    const int wlo = wt << 6;                           // first row of window

    const int off_b  = offs[wb];
    const int cnt_b  = offs[wb + 1] - off_b;
    const int npairs = cnt_b * 32;

    // ---- pass 1: count this thread's owned bins (exact ownership test) ----
    int c = 0;
    for (int q = tid; q < npairs; q += 512) {
        const int n = order[off_b + (q >> 5)];
        if ((bin_r_first(boxes, n, q & 31) >> 6) == wt) ++c;
    }
    // wave-inclusive scan of c
    int sc = c;
    #pragma unroll
    for (int d = 1; d < 64; d <<= 1) {
        const int v = __shfl_up(sc, d);
        if (lane >= d) sc += v;
    }
    if (lane == 63) wsum[wv] = sc;
    __syncthreads();
    if (tid == 0) {
        int s = 0;
        for (int i = 0; i < 8; ++i) { const int t = wsum[i]; wsum[i] = s; s += t; }
        wsum[8] = s;
    }
    __syncthreads();
    const int K = wsum[8];                             // window's total bins
    if (K == 0) return;                                // empty: exit pre-staging

    if (K > LCAP_) {                                   // adversarial-only bail:
        // tile-less exact streaming; segs x waves partition boxes. Correct for
        // any data (ownership test unchanged), never taken on bench data.
        const int slot = seg * 8 + wv;                 // 0..31
        for (int j = slot; j < cnt_b; j += 32) {
            const int n = __builtin_amdgcn_readfirstlane(order[off_b + j]);
            bool in = false;
            if (lane < 32) in = ((bin_r_first(boxes, n, lane) >> 6) == wt);
            unsigned long long m = __ballot(in);
            while (m) {
                const int p = __builtin_ctzll(m);
                m &= m - 1;
                process_bin(feat, boxes, batch_idx, out, nullptr, 0, 0, (n << 5) | p, lane);
            }
        }
        return;
    }

    // ---- pass 2: write owned bins at deterministic offsets ----
    int o = wsum[wv] + (sc - c);                       // exclusive thread offset
    for (int q = tid; q < npairs; q += 512) {
        const int n = order[off_b + (q >> 5)];
        const int p = q & 31;
        if ((bin_r_first(boxes, n, p) >> 6) == wt)
            list[o++] = (unsigned short)((n << 5) | p);
    }

    // ---- stage window: 8 waves x 8 rows, direct global->LDS (lane*16B) ----
    {
        const int r0 = wv * 8;
        const float* srow = feat + ((long)wb * LV_ + wlo + r0) * D_ + lane * 4;
        v4f* lrow = tile + r0 * 64;
#if __has_builtin(__builtin_amdgcn_global_load_lds)
        #pragma unroll
        for (int j = 0; j < 8; ++j) {
            __builtin_amdgcn_global_load_lds(
                (const __attribute__((address_space(1))) void*)(srow + j * D_),
                (__attribute__((address_space(3))) void*)(lrow + j * 64),
                16, 0, 0);
        }
#else
        const v4f* src = (const v4f*)feat + ((long)wb * LV_ + wlo + r0) * (D_ / 4) + lane;
        v4f t0 = src[0],   t1 = src[64],  t2 = src[128], t3 = src[192];
        v4f t4 = src[256], t5 = src[320], t6 = src[384], t7 = src[448];
        v4f* dst = lrow + lane;
        dst[0]   = t0; dst[64]  = t1; dst[128] = t2; dst[192] = t3;
        dst[256] = t4; dst[320] = t5; dst[384] = t6; dst[448] = t7;
#endif
    }
    __syncthreads();                                   // list + tile both ready

    // ---- process: R7-style balanced interleave over the shared list ----
    for (int i = seg + 4 * wv; i < K; i += SEGS_ * 8) {
        const int idx = __builtin_amdgcn_readfirstlane((int)list[i]);
        process_bin(feat, boxes, batch_idx, out, tile, wb, wlo, idx, lane);
    }
}

// Emergency fallback (workspace too small): direct global-path kernel.
__global__ __launch_bounds__(256) void roi_plain_kernel(
    const float* __restrict__ feat, const float* __restrict__ boxes,
    const int* __restrict__ batch_idx, float* __restrict__ out)
{
    const int slot = blockIdx.x * 4 + (threadIdx.x >> 6);
    const int lane = threadIdx.x & 63;
    process_bin(feat, boxes, batch_idx, out, nullptr, 0, 0, slot, lane);
}

extern "C" void kernel_launch(void* const* d_in, const int* in_sizes, int n_in,
                              void* d_out, int out_size, void* d_ws, size_t ws_size,
                              hipStream_t stream) {
    const float* feat      = (const float*)d_in[0];
    const float* boxes     = (const float*)d_in[1];
    const int*   batch_idx = (const int*)d_in[2];
    float*       out       = (float*)d_out;

    if (ws_size >= (size_t)(N_ + B_ + 1) * sizeof(int)) {
        int* order = (int*)d_ws;                       // [N_]
        int* offs  = order + N_;                       // [B_+1]
        build_order_kernel<<<1, 256, 0, stream>>>(batch_idx, order, offs);
        roi_win_kernel<<<NBLK_, 512, 0, stream>>>(feat, boxes, batch_idx, order, offs, out);
    } else {
        roi_plain_kernel<<<(N_ * P_) / 4, 256, 0, stream>>>(feat, boxes, batch_idx, out);
    }
}